// Round 7
// baseline (276.498 us; speedup 1.0000x reference)
//
#include <hip/hip_runtime.h>
#include <stdint.h>

typedef __attribute__((ext_vector_type(8))) short bf16x8;
typedef __attribute__((ext_vector_type(4))) float f32x4;
typedef __attribute__((ext_vector_type(4))) unsigned short u16x4;
typedef __attribute__((ext_vector_type(4))) unsigned int u32x4;

#define NB 32
#define HH 128
#define WW 128
#define CI 128
#define CO 128
#define HO 126
#define WO 126
#define TH 16
#define TW 16
#define PHh 18
#define PWw 18
#define NROW (PHh * PWw)   // 324 patch rows
// fallback (R4) layout
#define RSTR 72
#define RSTRB 144
// bf16-X fast path: ws layout [ktr 9437184][zeropage 1024][xbf 134217728]
#define ZOFF 9437184u
#define XOFF 9438208u
#define QROWS 336          // 324 rows padded to 21 x 16-row wave-instr groups
#define QBYTES (QROWS * 64)  // 21504 B per ci-quarter buffer

__device__ __forceinline__ unsigned short f2bf(float f) {
  union { float f; unsigned u; } x; x.f = f;
  unsigned u = x.u;
  u += 0x7FFFu + ((u >> 16) & 1u);   // RNE round to bf16
  return (unsigned short)(u >> 16);
}

// cvt_pk_bf16_f32: RNE, packs 2 f32 -> 2 bf16 in one VALU op (no builtin on gfx950)
__device__ __forceinline__ unsigned cvtpk_bf16(float a, float b) {
  unsigned r;
  asm("v_cvt_pk_bf16_f32 %0, %1, %2" : "=v"(r) : "v"(a), "v"(b));
  return r;  // low16 = bf16(a), high16 = bf16(b)
}

// prep: [b,p][ci][co] f32 -> fragment-blocked bf16, slice-major [b][ch][p][kc]:
//   slice = (ch*9+p)*2+kc (4096 shorts each); within: f*512 + lane*8 + e
//   holds kin[b,p][ci = ch*64+kc*32+(lane>>4)*8+e][co = (f>>2)*64+(f&3)*16+(lane&15)]
__global__ void prep_kt(const float* __restrict__ kin, unsigned short* __restrict__ ktr) {
  __shared__ unsigned short t[CI * CO];  // 32 KB
  int bp = blockIdx.x;  // b*9+p, 0..287
  int b = bp / 9, p = bp % 9;
  const float* src = kin + (size_t)bp * (CI * CO);
  unsigned short* dstb = ktr + (size_t)b * (9 * CI * CO);
  for (int i = threadIdx.x; i < CI * CO / 4; i += blockDim.x) {
    f32x4 v = *(const f32x4*)(src + i * 4);
    u16x4 o;
    o.x = f2bf(v.x); o.y = f2bf(v.y); o.z = f2bf(v.z); o.w = f2bf(v.w);
    *(u16x4*)&t[i * 4] = o;
  }
  __syncthreads();
  for (int j = threadIdx.x; j < 2048; j += blockDim.x) {  // j = (sl*8+f)*64+lane
    int lane = j & 63, f = (j >> 6) & 7, sl = j >> 9;     // sl = ch*2+kc
    int ch = sl >> 1, kc = sl & 1;
    int co = (f >> 2) * 64 + (f & 3) * 16 + (lane & 15);
    int ci0 = ch * 64 + kc * 32 + (lane >> 4) * 8;
    bf16x8 v;
#pragma unroll
    for (int e = 0; e < 8; ++e) v[e] = t[(ci0 + e) * CO + co];
    int slice = (ch * 9 + p) * 2 + kc;
    *(bf16x8*)&dstb[(size_t)slice * 4096 + f * 512 + lane * 8] = v;
  }
}

// X fp32 -> bf16 prepass (one-time 402 MB streaming; removes ALL conversion
// VALU + halves staging bytes in the main kernel, enabling pure
// global_load_lds staging there). Also zeroes the halo zero-page.
__global__ void prep_x(const float* __restrict__ X, char* __restrict__ ws) {
  if (blockIdx.x == 0 && threadIdx.x < 256)
    ((unsigned*)(ws + ZOFF))[threadIdx.x] = 0u;
  unsigned short* xb = (unsigned short*)(ws + XOFF);
  const int total = NB * HH * WW * CI / 8;   // 8,388,608 iters of 8 elems
  int stride = gridDim.x * blockDim.x;
  for (int i = blockIdx.x * blockDim.x + threadIdx.x; i < total; i += stride) {
    f32x4 a = *(const f32x4*)(X + (size_t)i * 8);
    f32x4 c = *(const f32x4*)(X + (size_t)i * 8 + 4);
    u32x4 o;
    o.x = cvtpk_bf16(a.x, a.y);
    o.y = cvtpk_bf16(a.z, a.w);
    o.z = cvtpk_bf16(c.x, c.y);
    o.w = cvtpk_bf16(c.z, c.w);
    *(u32x4*)(xb + (size_t)i * 8) = o;
  }
}

// naive fallback (only if ws_size too small — not expected on this harness)
__global__ void conv_naive(const float* __restrict__ X, const float* __restrict__ Kf,
                           float* __restrict__ out) {
  int idx = blockIdx.x * blockDim.x + threadIdx.x;           // over B*HO*WO*CO
  if (idx >= NB * HO * WO * CO) return;
  int co = idx & 127, t = idx >> 7;
  int wp = t % WO; t /= WO;
  int hp = t % HO; int b = t / HO;
  const float* xb = X + (size_t)b * HH * WW * CI;
  const float* kb = Kf + (size_t)b * 9 * CI * CO;
  float s = 0.f;
  for (int p = 0; p < 9; ++p) {
    int kh = p / 3, kw = p % 3;
    const float* xr = xb + ((size_t)(hp + kh) * WW + (wp + kw)) * CI;
    const float* kr = kb + (size_t)p * CI * CO + co;
    for (int ci = 0; ci < CI; ++ci) s += xr[ci] * kr[(size_t)ci * CO];
  }
  out[idx] = s;
}

// ---------------- fast path: bf16-X, global_load_lds staging ----------------
__global__ __launch_bounds__(512, 4) void conv_main_bf(
    const char* __restrict__ ws, float* __restrict__ out) {
  // ci-quarter (32 ci = 64 B/row) ping-pong buffers, LINEAR rows: stride
  // 64 B = 16 dwords -> wave read pattern (16lr+4ks) mod 32 lands 8 dwords
  // per bank (the b128 minimum) -> conflict-balanced without swizzle, so
  // every compute LDS address is base + compile-time immediate (anti-spill)
  // AND the layout is global_load_lds-compatible (linear dest, m104).
  __shared__ char lds_q[2][QBYTES];   // 43008 B -> 2 blocks/CU

  const int tid = threadIdx.x;
  const int lane = tid & 63;
  const int wid = tid >> 6;            // 8 waves, 4 (h) x 2 (co)
  const int wr = wid >> 1, wc = wid & 1;

  // XCD-clustered block swizzle (verified: FETCH 200->146MB).
  const int l = blockIdx.x;            // 0..2047
  const int xcd = l & 7, j = l >> 3;   // j: 0..255
  const int b = xcd * 4 + (j >> 6);    // 4 batches per XCD
  const int t = j & 63;                // tile within batch (8x8 of 16x16)
  const int ht = t >> 3, wt = t & 7;
  const int h0 = ht * TH, w0 = wt * TW;
  const int ks = lane >> 4, lr = lane & 15;

  // ---- staging: 21 wave-instrs of 1KB per quarter; wave w issues k=0..2
  // (j = wid+8k < 21). Lane covers slot s = j*64... : row = j*16+(lane>>2),
  // chunk c = lane&3 (16 B = 8 ci). Global src precomputed once; quarter q
  // adds q*64 B (ci offset within the 256 B pixel). Halo/pad -> zero-page.
  unsigned pofs[3];
  {
    const unsigned xbo = XOFF + ((unsigned)b << 22);   // b * 4 MB
#pragma unroll
    for (int k = 0; k < 3; ++k) {
      int jj = wid + k * 8;
      int row = jj * 16 + (lane >> 2);
      int c = lane & 3;
      int h = row / PWw, w = row - h * PWw;
      int gh = h0 + h, gw = w0 + w;
      bool ok = (row < NROW) && ((unsigned)(gh | gw) < 128u);
      pofs[k] = ok ? xbo + ((unsigned)(((gh & 127) << 7) + (gw & 127)) << 8) + (c << 4)
                   : ZOFF + (unsigned)(c << 4);
    }
  }
  auto stageQ = [&](int q, int buf) {
#pragma unroll
    for (int k = 0; k < 3; ++k) {
      int jj = wid + k * 8;
      if (jj < 21) {                   // wave-uniform branch
        unsigned lo = (unsigned)(buf * QBYTES + jj * 1024);
        lo = __builtin_amdgcn_readfirstlane(lo);
        const char* ga = ws + pofs[k] + (q << 6);
        __builtin_amdgcn_global_load_lds(
            (const __attribute__((address_space(1))) void*)ga,
            (__attribute__((address_space(3))) void*)(&lds_q[0][0] + lo), 16, 0, 0);
      }
    }
  };

  // compute read base: row(m,kh,kw) = (wr*4+m+kh)*18 + lr + kw, byte =
  // row*64 + ks*16 = aoff + imm, imm = ((m+kh)*18+kw)*64 (compile-time).
  const int aoff = ((wr * 4) * PWw + lr) * 64 + ks * 16;

  // B slices: quarter q -> slice base (q>>1)*18 + (q&1), cluster p adds 2
  // slices (8192 shorts); 4 contiguous 1KB bursts per wave (L2-resident).
  const unsigned short* ktw = (const unsigned short*)ws +
                              (size_t)b * 9 * CI * CO + (wc * 4) * 512 + lane * 8;
  bf16x8 Hf[4];
  auto loadB = [&](const unsigned short* p) {
#pragma unroll
    for (int n = 0; n < 4; ++n)
      Hf[n] = *(const bf16x8*)(p + n * 512);
  };

  f32x4 zero = {0.f, 0.f, 0.f, 0.f};
  f32x4 acc[4][4];
#pragma unroll
  for (int m = 0; m < 4; ++m)
#pragma unroll
    for (int n = 0; n < 4; ++n) acc[m][n] = zero;

  // prologue: stage quarter 0 into buf0, prefetch B(q0,p0)
  stageQ(0, 0);
  loadB(ktw);
  __syncthreads();                     // drains stage + B (vmcnt 0)

#pragma unroll 1
  for (int q = 0; q < 4; ++q) {
    const char* rb = &lds_q[q & 1][0];
    const unsigned short* bq = ktw + (size_t)((q >> 1) * 18 + (q & 1)) * 4096;
    const unsigned short* bnext =
        ktw + (size_t)(((q + 1) >> 1) * 18 + ((q + 1) & 1)) * 4096;
#pragma unroll
    for (int p = 0; p < 9; ++p) {
      const int kh = p / 3, kw = p % 3;        // compile-time (unrolled)
      bf16x8 af[4];
#pragma unroll
      for (int m = 0; m < 4; ++m)
        af[m] = *(const bf16x8*)(rb + aoff + ((m + kh) * PWw + kw) * 64);
      __builtin_amdgcn_s_setprio(1);
#pragma unroll
      for (int m = 0; m < 4; ++m)
#pragma unroll
        for (int n = 0; n < 4; ++n)
          acc[m][n] = __builtin_amdgcn_mfma_f32_16x16x32_bf16(af[m], Hf[n], acc[m][n], 0, 0, 0);
      __builtin_amdgcn_s_setprio(0);
      if (p < 8) loadB(bq + (size_t)(p + 1) * 8192);   // WAR on Hf: MFMAs issued
      else if (q < 3) loadB(bnext);
      // issue next-quarter stage right after cluster 0's B-prefetch: its
      // loads drain under the remaining 8 MFMA clusters (~700 cyc)
      if (p == 0 && q < 3) stageQ(q + 1, (q & 1) ^ 1);
    }
    if (q < 3) __syncthreads();        // stage(q+1) visible to all waves
  }

  // ---- epilogue: C/D map col=lane&15 (cout), row=(lane>>4)*4+reg (pw) ----
  float* ob = out + (size_t)b * HO * WO * CO;
#pragma unroll
  for (int m = 0; m < 4; ++m) {
    int hp = h0 + wr * 4 + m;
    if (hp >= HO) continue;
#pragma unroll
    for (int r = 0; r < 4; ++r) {
      int wp = w0 + ks * 4 + r;
      if (wp >= WO) continue;
#pragma unroll
      for (int n = 0; n < 4; ++n) {
        int co = wc * 64 + n * 16 + lr;
        ob[((size_t)hp * WO + wp) * CO + co] = acc[m][n][r];
      }
    }
  }
}

// ---------------- fallback: proven R4 kernel (fp32 staging) ----------------
__global__ __launch_bounds__(512, 4) void conv_main(
    const float* __restrict__ X, const unsigned short* __restrict__ Kt,
    float* __restrict__ out) {
  __shared__ unsigned short lds_a[NROW * RSTR];  // 46656 B -> 2 blocks/CU

  const int tid = threadIdx.x;
  const int lane = tid & 63;
  const int wid = tid >> 6;
  const int wr = wid >> 1, wc = wid & 1;
  const int l = blockIdx.x;
  const int xcd = l & 7, j = l >> 3;
  const int b = xcd * 4 + (j >> 6);
  const int t = j & 63;
  const int ht = t >> 3, wt = t & 7;
  const int h0 = ht * TH, w0 = wt * TW;
  const int ks = lane >> 4, lr = lane & 15;

  const float* xb = X + (size_t)b * HH * WW * CI;
  const int ci4 = tid & 15;
  const int row0 = tid >> 4;
  const int hi0 = (row0 >= PWw) ? 1 : 0;
  const int wi0 = row0 - hi0 * PWw;
  char* const dst0 = (char*)lds_a + row0 * RSTRB + ci4 * 8;

  auto stageA = [&](int ch) {
    int h = hi0, w = wi0;
    const float* srcb = xb + ch * 64 + ci4 * 4;
#pragma unroll
    for (int k = 0; k < 11; ++k) {
      if (k < 10 || tid < 64) {
        int gh = h0 + h, gw = w0 + w;
        bool ok = (gh | gw) < HH;
        const float* src = srcb + ((size_t)(((gh & 127) << 7) + (gw & 127)) << 7);
        f32x4 v = *(const f32x4*)src;
        uint2 o;
        o.x = ok ? cvtpk_bf16(v.x, v.y) : 0u;
        o.y = ok ? cvtpk_bf16(v.z, v.w) : 0u;
        *(uint2*)(dst0 + k * (32 * RSTRB)) = o;
      }
      w += 14;
      int wrap = (w >= PWw) ? 1 : 0;
      h += 1 + wrap;
      w -= wrap ? PWw : 0;
    }
  };

  const int aoff = ((wr * 4) * PWw + lr) * RSTRB + ks * 16;
  const char* ldsb = (const char*)lds_a;

  f32x4 zero = {0.f, 0.f, 0.f, 0.f};
  f32x4 acc[4][4];
#pragma unroll
  for (int m = 0; m < 4; ++m)
#pragma unroll
    for (int n = 0; n < 4; ++n) acc[m][n] = zero;

  const unsigned short* ktw = Kt + (size_t)b * 9 * CI * CO + (wc * 4) * 512 + lane * 8;
  bf16x8 Hf[4];
  auto loadBh = [&](int slice) {
#pragma unroll
    for (int n = 0; n < 4; ++n)
      Hf[n] = *(const bf16x8*)&ktw[(size_t)slice * 4096 + n * 512];
  };

#pragma unroll 1
  for (int ch = 0; ch < 2; ++ch) {
    if (ch) __syncthreads();
    loadBh(ch * 18);
    stageA(ch);
    __syncthreads();
#pragma unroll
    for (int kh = 0; kh < 3; ++kh) {
#pragma unroll
      for (int jj = 0; jj < 6; ++jj) {
        const int kw = jj >> 1, kc = jj & 1;
        const int s = kh * 6 + jj;
        bf16x8 af[4];
#pragma unroll
        for (int m = 0; m < 4; ++m)
          af[m] = *(const bf16x8*)(ldsb + aoff +
                                   ((m + kh) * PWw * RSTRB + kw * RSTRB + kc * 64));
        __builtin_amdgcn_s_setprio(1);
#pragma unroll
        for (int m = 0; m < 4; ++m)
#pragma unroll
          for (int n = 0; n < 4; ++n)
            acc[m][n] = __builtin_amdgcn_mfma_f32_16x16x32_bf16(af[m], Hf[n], acc[m][n], 0, 0, 0);
        __builtin_amdgcn_s_setprio(0);
        if (s < 17) loadBh(ch * 18 + s + 1);
      }
    }
  }

  float* ob = out + (size_t)b * HO * WO * CO;
#pragma unroll
  for (int m = 0; m < 4; ++m) {
    int hp = h0 + wr * 4 + m;
    if (hp >= HO) continue;
#pragma unroll
    for (int r = 0; r < 4; ++r) {
      int wp = w0 + ks * 4 + r;
      if (wp >= WO) continue;
#pragma unroll
      for (int n = 0; n < 4; ++n) {
        int co = wc * 64 + n * 16 + lr;
        ob[((size_t)hp * WO + wp) * CO + co] = acc[m][n][r];
      }
    }
  }
}

extern "C" void kernel_launch(void* const* d_in, const int* in_sizes, int n_in,
                              void* d_out, int out_size, void* d_ws, size_t ws_size,
                              hipStream_t stream) {
  const float* X = (const float*)d_in[0];
  const float* Kf = (const float*)d_in[1];
  float* out = (float*)d_out;
  size_t need_small = (size_t)NB * 9 * CI * CO * sizeof(unsigned short);  // 9.4 MB
  size_t need_big = (size_t)XOFF + (size_t)NB * HH * WW * CI * 2;         // 143.7 MB
  if (d_ws != nullptr && ws_size >= need_big) {
    char* ws = (char*)d_ws;
    prep_kt<<<dim3(NB * 9), 256, 0, stream>>>(Kf, (unsigned short*)ws);
    prep_x<<<dim3(4096), 256, 0, stream>>>(X, ws);
    conv_main_bf<<<dim3(2048), 512, 0, stream>>>(ws, out);
  } else if (d_ws != nullptr && ws_size >= need_small) {
    unsigned short* ktr = (unsigned short*)d_ws;
    prep_kt<<<dim3(NB * 9), 256, 0, stream>>>(Kf, ktr);
    conv_main<<<dim3(2048), 512, 0, stream>>>(X, ktr, out);
  } else {
    int total = NB * HO * WO * CO;
    conv_naive<<<(total + 255) / 256, 256, 0, stream>>>(X, Kf, out);
  }
}

// Round 9
// 232.163 us; speedup vs baseline: 1.1910x; 1.1910x over previous
//
#include <hip/hip_runtime.h>
#include <stdint.h>

typedef __attribute__((ext_vector_type(8))) short bf16x8;
typedef __attribute__((ext_vector_type(4))) float f32x4;
typedef __attribute__((ext_vector_type(4))) unsigned short u16x4;

#define NB 32
#define HH 128
#define WW 128
#define CI 128
#define CO 128
#define HO 126
#define WO 126
#define TH 8            // output tile h (4-wave, 256-thread blocks)
#define TW 16
#define PHh 10          // patch h = TH + 2
#define PWw 18          // patch w = TW + 2
#define NROW (PHh * PWw)   // 180 patch rows
#define RSTR 72            // shorts per LDS row (144 B) — affine, immediates only
#define RSTRB 144

__device__ __forceinline__ unsigned short f2bf(float f) {
  union { float f; unsigned u; } x; x.f = f;
  unsigned u = x.u;
  u += 0x7FFFu + ((u >> 16) & 1u);   // RNE round to bf16
  return (unsigned short)(u >> 16);
}

// cvt_pk_bf16_f32: RNE, packs 2 f32 -> 2 bf16 in one VALU op (no builtin on gfx950)
__device__ __forceinline__ unsigned cvtpk_bf16(float a, float b) {
  unsigned r;
  asm("v_cvt_pk_bf16_f32 %0, %1, %2" : "=v"(r) : "v"(a), "v"(b));
  return r;  // low16 = bf16(a), high16 = bf16(b)
}

// prep: [b,p][ci][co] f32 -> fragment-blocked bf16, slice-major [b][ch][p][kc]:
//   slice = (ch*9+p)*2+kc (4096 shorts each); within: f*512 + lane*8 + e
//   holds kin[b,p][ci = ch*64+kc*32+(lane>>4)*8+e][co = (f>>2)*64+(f&3)*16+(lane&15)]
__global__ void prep_kt(const float* __restrict__ kin, unsigned short* __restrict__ ktr) {
  __shared__ unsigned short t[CI * CO];  // 32 KB
  int bp = blockIdx.x;  // b*9+p, 0..287
  int b = bp / 9, p = bp % 9;
  const float* src = kin + (size_t)bp * (CI * CO);
  unsigned short* dstb = ktr + (size_t)b * (9 * CI * CO);
  for (int i = threadIdx.x; i < CI * CO / 4; i += blockDim.x) {
    f32x4 v = *(const f32x4*)(src + i * 4);
    u16x4 o;
    o.x = f2bf(v.x); o.y = f2bf(v.y); o.z = f2bf(v.z); o.w = f2bf(v.w);
    *(u16x4*)&t[i * 4] = o;
  }
  __syncthreads();
  for (int j = threadIdx.x; j < 2048; j += blockDim.x) {  // j = (sl*8+f)*64+lane
    int lane = j & 63, f = (j >> 6) & 7, sl = j >> 9;     // sl = ch*2+kc
    int ch = sl >> 1, kc = sl & 1;
    int co = (f >> 2) * 64 + (f & 3) * 16 + (lane & 15);
    int ci0 = ch * 64 + kc * 32 + (lane >> 4) * 8;
    bf16x8 v;
#pragma unroll
    for (int e = 0; e < 8; ++e) v[e] = t[(ci0 + e) * CO + co];
    int slice = (ch * 9 + p) * 2 + kc;
    *(bf16x8*)&dstb[(size_t)slice * 4096 + f * 512 + lane * 8] = v;
  }
}

// naive fallback (only if ws_size too small — not expected on this harness)
__global__ void conv_naive(const float* __restrict__ X, const float* __restrict__ Kf,
                           float* __restrict__ out) {
  int idx = blockIdx.x * blockDim.x + threadIdx.x;           // over B*HO*WO*CO
  if (idx >= NB * HO * WO * CO) return;
  int co = idx & 127, t = idx >> 7;
  int wp = t % WO; t /= WO;
  int hp = t % HO; int b = t / HO;
  const float* xb = X + (size_t)b * HH * WW * CI;
  const float* kb = Kf + (size_t)b * 9 * CI * CO;
  float s = 0.f;
  for (int p = 0; p < 9; ++p) {
    int kh = p / 3, kw = p % 3;
    const float* xr = xb + ((size_t)(hp + kh) * WW + (wp + kw)) * CI;
    const float* kr = kb + (size_t)p * CI * CO + co;
    for (int ci = 0; ci < CI; ++ci) s += xr[ci] * kr[(size_t)ci * CO];
  }
  out[idx] = s;
}

// 256-thread blocks at 3 blocks/CU (__launch_bounds__(256,3) -> ~170 regs/thd):
// the register headroom funds an af DOUBLE-BUFFER, so cluster s+1's ds_reads
// are issued before cluster s's MFMAs and the per-cluster LDS latency
// (~150-300cy under load — the pinned-35%-MfmaUtil cause across R0/R4/R7)
// hides under the 16-MFMA cluster. (R8 had an off-by-one: the second
// sub-step prefetched cluster s+2 instead of s+1 — fixed here.)
__global__ __launch_bounds__(256, 3) void conv_main(
    const float* __restrict__ X, const unsigned short* __restrict__ Kt,
    float* __restrict__ out) {
  // One Cin-half of the 10x18 patch; rows padded to 144 B: every compute LDS
  // address is base + compile-time immediate (anti-spill invariant, R3/R4).
  __shared__ unsigned short lds_a[NROW * RSTR];  // 25920 B -> 3 blocks/CU

  const int tid = threadIdx.x;
  const int lane = tid & 63;
  const int wid = tid >> 6;            // 4 waves, 2 (h) x 2 (co)
  const int wr = wid >> 1, wc = wid & 1;

  // XCD-clustered block swizzle: 4 whole batches per XCD (L2-resident B).
  const int l = blockIdx.x;            // 0..4095
  const int xcd = l & 7, j = l >> 3;   // j: 0..511
  const int b = xcd * 4 + (j >> 7);    // 4 batches per XCD
  const int t = j & 127;               // tile within batch (16h x 8w)
  const int ht = t >> 3, wt = t & 7;
  const int h0 = ht * TH, w0 = wt * TW;
  const int ks = lane >> 4, lr = lane & 15;

  const float* xb = X + (size_t)b * HH * WW * CI;

  // ---- stage: slot s = tid + k*256; row = (tid>>4) + 16k; ci4 = tid&15 ----
  // affine: dst byte = row*144 + ci4*8, advances 2304 B per k (ds imm).
  const int ci4 = tid & 15;
  const int row0 = tid >> 4;                  // 0..15 (all h=0, w=row0)
  char* const dst0 = (char*)lds_a + row0 * RSTRB + ci4 * 8;

  auto stageA = [&](int ch) {
    int h = 0, w = row0;
    const float* srcb = xb + ch * 64 + ci4 * 4;
#pragma unroll
    for (int k = 0; k < 12; ++k) {            // 11 full rounds + 4-row tail
      if (k < 11 || tid < 64) {
        int gh = h0 + h, gw = w0 + w;
        bool ok = (gh | gw) < HH;             // gh<128 && gw<128 (both <256)
        const float* src = srcb + ((size_t)(((gh & 127) << 7) + (gw & 127)) << 7);
        f32x4 v = *(const f32x4*)src;
        uint2 o;
        o.x = ok ? cvtpk_bf16(v.x, v.y) : 0u;
        o.y = ok ? cvtpk_bf16(v.z, v.w) : 0u;
        *(uint2*)(dst0 + k * (16 * RSTRB)) = o;  // folds into ds imm
      }
      w += 16;                                // advance 16 rows
      if (w >= PWw) { w -= PWw; h += 1; }
    }
  };

  // ---- compute: af byte = aoff + ((m+kh)*18 + kw)*144 + kc*64 (imm) ----
  const int aoff = ((wr * 4) * PWw + lr) * RSTRB + ks * 16;
  const char* ldsb = (const char*)lds_a;

  f32x4 zero = {0.f, 0.f, 0.f, 0.f};
  f32x4 acc[4][4];
#pragma unroll
  for (int m = 0; m < 4; ++m)
#pragma unroll
    for (int n = 0; n < 4; ++n) acc[m][n] = zero;

  // B slices: slice = (ch*9+p)*2+kc = ch*18 + s; 4 contiguous 1KB bursts.
  const unsigned short* ktw = Kt + (size_t)b * 9 * CI * CO + (wc * 4) * 512 + lane * 8;
  bf16x8 Hf[4];
  auto loadBh = [&](int slice) {
#pragma unroll
    for (int n = 0; n < 4; ++n)
      Hf[n] = *(const bf16x8*)&ktw[(size_t)slice * 4096 + n * 512];
  };

  bf16x8 afA[4], afB[4];
  auto issueAf = [&](bf16x8 (&dst)[4], int s) {   // s compile-time via unroll
    const int kh = s / 6, jj = s % 6;
    const int kw = jj >> 1, kc = jj & 1;
#pragma unroll
    for (int m = 0; m < 4; ++m)
      dst[m] = *(const bf16x8*)(ldsb + aoff +
                                ((m + kh) * PWw * RSTRB + kw * RSTRB + kc * 64));
  };
  auto mma = [&](bf16x8 (&use)[4]) {
    __builtin_amdgcn_s_setprio(1);
#pragma unroll
    for (int m = 0; m < 4; ++m)
#pragma unroll
      for (int n = 0; n < 4; ++n)
        acc[m][n] = __builtin_amdgcn_mfma_f32_16x16x32_bf16(use[m], Hf[n], acc[m][n], 0, 0, 0);
    __builtin_amdgcn_s_setprio(0);
  };

#pragma unroll 1
  for (int ch = 0; ch < 2; ++ch) {
    if (ch) __syncthreads();           // all waves done reading previous half
    loadBh(ch * 18);                   // B prefetch flies during staging
    stageA(ch);
    __syncthreads();                   // lds_a ready
    issueAf(afA, 0);                   // prime the af pipeline
#pragma unroll
    for (int u = 0; u < 9; ++u) {      // 18 clusters as 9 ping-pong pairs
      {
        const int s = 2 * u;
        issueAf(afB, s + 1);           // fly during afA's MFMAs
        mma(afA);                      // cluster s with Hf = slice s
        loadBh(ch * 18 + s + 1);       // WAR on Hf: safe, MFMAs issued
      }
      {
        const int s = 2 * u + 1;
        if (s < 17) issueAf(afA, s + 1);   // cluster s+1 (R8 bug: was s+2)
        mma(afB);                      // cluster s with Hf = slice s
        if (s < 17) loadBh(ch * 18 + s + 1);
      }
    }
  }

  // ---- epilogue: C/D map col=lane&15 (cout), row=(lane>>4)*4+reg (pw) ----
  float* ob = out + (size_t)b * HO * WO * CO;
#pragma unroll
  for (int m = 0; m < 4; ++m) {
    int hp = h0 + wr * 4 + m;
    if (hp >= HO) continue;
#pragma unroll
    for (int r = 0; r < 4; ++r) {
      int wp = w0 + ks * 4 + r;
      if (wp >= WO) continue;
#pragma unroll
      for (int n = 0; n < 4; ++n) {
        int co = wc * 64 + n * 16 + lr;
        ob[((size_t)hp * WO + wp) * CO + co] = acc[m][n][r];
      }
    }
  }
}

extern "C" void kernel_launch(void* const* d_in, const int* in_sizes, int n_in,
                              void* d_out, int out_size, void* d_ws, size_t ws_size,
                              hipStream_t stream) {
  const float* X = (const float*)d_in[0];
  const float* Kf = (const float*)d_in[1];
  float* out = (float*)d_out;
  size_t need = (size_t)NB * 9 * CI * CO * sizeof(unsigned short);  // 9.4 MB
  if (d_ws != nullptr && ws_size >= need) {
    unsigned short* ktr = (unsigned short*)d_ws;
    prep_kt<<<dim3(NB * 9), 256, 0, stream>>>(Kf, ktr);
    conv_main<<<dim3(4096), 256, 0, stream>>>(X, ktr, out);
  } else {
    int total = NB * HO * WO * CO;
    conv_naive<<<(total + 255) / 256, 256, 0, stream>>>(X, Kf, out);
  }
}